// Round 4
// baseline (172.025 us; speedup 1.0000x reference)
//
#include <hip/hip_runtime.h>

// StructNConv2D_d_with_s — fused spatial (3x3) + channel (16x16) normalized conv.
// d,cd: (4,16,256,256) f32; s_prod_roll: (4,16,9,256,256) f32;
// spatial_weight: (16,1,9,1,1); channel_weight: (16,16,1,1).
// Outputs concatenated: d_out then cd_out, each (4,16,256,256) f32.
//
// R4: manual software pipeline over channels — s_prod_roll loads (the
// HBM-latency stream, 76% of traffic) double-buffered one c-iteration
// ahead (spA/spB, static indexing). d/cd are L2/L3-resident (stencil
// reuse) and stay inline. v_rcp_f32 replaces exact divides (tol 2.1e-2).
// launch_bounds(128,3): VGPR cap 170 for the +18-reg prefetch buffer.

#define NB 4
#define NC 16
#define NH 256
#define NW 256
#define NK 9
#define HW (NH * NW)
#define TPB 128

static constexpr float kEPS = 1e-20f;

__device__ __forceinline__ float frcp(float x) {
    return __builtin_amdgcn_rcpf(x);
}

__global__ __launch_bounds__(TPB, 3) void structnconv_fused(
    const float* __restrict__ g_d,
    const float* __restrict__ g_cd,
    const float* __restrict__ g_sp,   // s_prod_roll
    const float* __restrict__ g_sw,   // spatial_weight (16*9)
    const float* __restrict__ g_cw,   // channel_weight (16*16)
    float* __restrict__ g_dout,
    float* __restrict__ g_cdout)
{
    __shared__ float lds_sw[NC * NK];   // 144
    __shared__ float lds_cw[NC * NC];   // 256
    __shared__ float lds_part[4];

    const int t = threadIdx.x;

    // Stage weights + their global sums (block-redundant, tiny).
    float s1 = g_sw[t];                       // t < 128 < 144
    float s2 = g_cw[t] + g_cw[TPB + t];
    lds_sw[t] = s1;
    lds_cw[t] = g_cw[t];
    lds_cw[TPB + t] = g_cw[TPB + t];
    if (t < NC * NK - TPB) {                  // 16 tail elements of sw
        const float v = g_sw[TPB + t];
        lds_sw[TPB + t] = v;
        s1 += v;
    }
    #pragma unroll
    for (int off = 32; off > 0; off >>= 1) {
        s1 += __shfl_down(s1, off);
        s2 += __shfl_down(s2, off);
    }
    if ((t & 63) == 0) {
        lds_part[t >> 6]       = s1;
        lds_part[2 + (t >> 6)] = s2;
    }
    __syncthreads();
    const float inv_sw_sum = frcp(lds_part[0] + lds_part[1] + kEPS);
    const float inv_cw_sum = frcp(lds_part[2] + lds_part[3] + kEPS);

    // Block -> one (b, h) row; thread -> 2 consecutive pixels.
    const int b  = blockIdx.x >> 8;
    const int h  = blockIdx.x & (NH - 1);
    const int w0 = t << 1;
    const int pix = h * NW + w0;

    float an0[NC], an1[NC], ad0[NC], ad1[NC];   // channel-mix accumulators
    #pragma unroll
    for (int o = 0; o < NC; ++o) { an0[o] = an1[o] = ad0[o] = ad1[o] = 0.f; }

    float2 spA[NK], spB[NK];

    #define LOADSP(dst, cc) do {                                              \
        const float* _p = g_sp + ((size_t)(b * NC + (cc)) * NK) * HW + pix;   \
        _Pragma("unroll")                                                     \
        for (int k = 0; k < NK; ++k)                                          \
            dst[k] = *(const float2*)(_p + (size_t)k * HW);                   \
    } while (0)

    auto compute = [&](int c, const float2* sp) {
        const float* pdd = g_d  + (size_t)(b * NC + c) * HW + pix;
        const float* pcc = g_cd + (size_t)(b * NC + c) * HW + pix;

        float nom0 = 0.f, nom1 = 0.f, den0 = 0.f, den1 = 0.f;
        #pragma unroll
        for (int r = 0; r < 3; ++r) {
            const int hh = h + r - 1;
            const bool rowok = (unsigned)hh < (unsigned)NH;   // uniform
            const int roff = (r - 1) * NW;
            float2 m_d = {0.f, 0.f}, m_c = {0.f, 0.f};
            float wl_d = 0.f, wr_d = 0.f, wl_c = 0.f, wr_c = 0.f;
            if (rowok) {
                m_d = *(const float2*)(pdd + roff);
                m_c = *(const float2*)(pcc + roff);
                if (w0 > 0)      { wl_d = pdd[roff - 1]; wl_c = pcc[roff - 1]; }
                if (w0 + 2 < NW) { wr_d = pdd[roff + 2]; wr_c = pcc[roff + 2]; }
            }
            const float cold[4] = {wl_d, m_d.x, m_d.y, wr_d};
            const float colc[4] = {wl_c, m_c.x, m_c.y, wr_c};
            #pragma unroll
            for (int dj = 0; dj < 3; ++dj) {
                const int k = r * 3 + dj;
                const float wck  = lds_sw[c * NK + k];
                const float cdp0 = colc[dj]     * sp[k].x;
                const float cdp1 = colc[dj + 1] * sp[k].y;
                nom0 = fmaf(cdp0 * cold[dj],     wck, nom0);
                den0 = fmaf(cdp0,                wck, den0);
                nom1 = fmaf(cdp1 * cold[dj + 1], wck, nom1);
                den1 = fmaf(cdp1,                wck, den1);
            }
        }
        const float dsp0 = nom0 * frcp(den0 + kEPS);
        const float dsp1 = nom1 * frcp(den1 + kEPS);
        const float cs0  = den0 * inv_sw_sum;
        const float cs1  = den1 * inv_sw_sum;
        const float pd0  = cs0 * dsp0;
        const float pd1  = cs1 * dsp1;

        #pragma unroll
        for (int o = 0; o < NC; ++o) {
            const float cwv = lds_cw[o * NC + c];
            an0[o] = fmaf(pd0, cwv, an0[o]);
            an1[o] = fmaf(pd1, cwv, an1[o]);
            ad0[o] = fmaf(cs0, cwv, ad0[o]);
            ad1[o] = fmaf(cs1, cwv, ad1[o]);
        }
    };

    // Software-pipelined channel loop: prefetch sp one iteration ahead.
    LOADSP(spA, 0);
    #pragma unroll 1
    for (int c = 0; c < NC; c += 2) {
        LOADSP(spB, c + 1);
        compute(c, spA);
        const int cn = (c + 2 < NC) ? (c + 2) : (NC - 1);  // clamp: no OOB
        LOADSP(spA, cn);
        compute(c + 1, spB);
    }
    #undef LOADSP

    // Epilogue: normalize + store (float2 per array per channel).
    const size_t outp = (size_t)b * NC * HW + pix;
    #pragma unroll
    for (int o = 0; o < NC; ++o) {
        float2 dv, cv;
        const float r2 = frcp(ad0[o] + kEPS);
        const float r3 = frcp(ad1[o] + kEPS);
        dv.x = an0[o] * r2;
        dv.y = an1[o] * r3;
        cv.x = ad0[o] * inv_cw_sum;     // devalue_conf == 1
        cv.y = ad1[o] * inv_cw_sum;
        *(float2*)(g_dout  + outp + (size_t)o * HW) = dv;
        *(float2*)(g_cdout + outp + (size_t)o * HW) = cv;
    }
}

extern "C" void kernel_launch(void* const* d_in, const int* in_sizes, int n_in,
                              void* d_out, int out_size, void* d_ws, size_t ws_size,
                              hipStream_t stream) {
    const float* g_d  = (const float*)d_in[0];
    const float* g_cd = (const float*)d_in[1];
    // d_in[2] = s, d_in[3] = cs : unused by the reference computation.
    const float* g_sp = (const float*)d_in[4];
    const float* g_sw = (const float*)d_in[5];
    const float* g_cw = (const float*)d_in[6];

    float* g_dout  = (float*)d_out;
    float* g_cdout = g_dout + (size_t)NB * NC * HW;

    const int blocks = NB * NH;   // 1024 blocks, one (b,h) row each
    structnconv_fused<<<blocks, TPB, 0, stream>>>(g_d, g_cd, g_sp, g_sw, g_cw,
                                                  g_dout, g_cdout);
}

// Round 5
// 41.196 us; speedup vs baseline: 4.1758x; 4.1758x over previous
//
#include <hip/hip_runtime.h>

// StructNConv2D_d_with_s — fused spatial (3x3) + channel (16x16) normalized conv.
// d,cd: (4,16,256,256) f32; s_prod_roll: (4,16,9,256,256) f32;
// spatial_weight: (16,1,9,1,1); channel_weight: (16,16,1,1).
// Outputs concatenated: d_out then cd_out, each (4,16,256,256) f32.
//
// R5: attack VMEM-instruction throughput (R2~R3 plateau at ~3.7 TB/s matches
// ~1 wave-vmem-instr/cy/CU on ~460 instrs/thread). 4 px/thread with float4
// loads/stores halves per-pixel instr count. Per-channel cs/pd park in
// thread-private LDS columns (no 128-reg accumulator blowup, no barriers:
// 1-wave blocks). TPB=64, block = one (b,h) row, 33KB LDS -> 4 blocks/CU.
// Bijective XCD swizzle (1024 = 8*128) gives each XCD a contiguous 128-row
// band for d/cd L2 locality. No pointers into register arrays (R4 lesson).

#define NB 4
#define NC 16
#define NH 256
#define NW 256
#define NK 9
#define HW (NH * NW)
#define TPB 64

static constexpr float kEPS = 1e-20f;

__device__ __forceinline__ float frcp(float x) { return __builtin_amdgcn_rcpf(x); }

__global__ __launch_bounds__(TPB) void structnconv_fused(
    const float* __restrict__ g_d,
    const float* __restrict__ g_cd,
    const float* __restrict__ g_sp,   // s_prod_roll
    const float* __restrict__ g_sw,   // spatial_weight (16*9)
    const float* __restrict__ g_cw,   // channel_weight (16*16)
    float* __restrict__ g_dout,
    float* __restrict__ g_cdout)
{
    __shared__ float lds_pd[NC][NW];    // cd_spatial*d_spatial, [c][w] 16KB
    __shared__ float lds_cs[NC][NW];    // cd_spatial,            [c][w] 16KB
    __shared__ float lds_sw[NC * NK];   // 144
    __shared__ float lds_cw[NC * NC];   // 256

    const int t = threadIdx.x;

    // ---- Stage weights + global sums (single wave: no barriers needed) ----
    const float a0 = g_sw[t], a1 = g_sw[64 + t];
    const float a2 = (t < NC * NK - 128) ? g_sw[128 + t] : 0.f;
    lds_sw[t] = a0;
    lds_sw[64 + t] = a1;
    if (t < NC * NK - 128) lds_sw[128 + t] = a2;
    const float c0 = g_cw[t], c1 = g_cw[64 + t], c2 = g_cw[128 + t], c3 = g_cw[192 + t];
    lds_cw[t] = c0; lds_cw[64 + t] = c1; lds_cw[128 + t] = c2; lds_cw[192 + t] = c3;
    float s1 = a0 + a1 + a2;
    float s2 = c0 + c1 + c2 + c3;
    #pragma unroll
    for (int off = 32; off > 0; off >>= 1) {
        s1 += __shfl_down(s1, off);
        s2 += __shfl_down(s2, off);
    }
    const float inv_sw_sum = frcp(__shfl(s1, 0) + kEPS);
    const float inv_cw_sum = frcp(__shfl(s2, 0) + kEPS);

    // ---- Block -> one (b,h) row via bijective XCD swizzle; thread -> 4 px ----
    const int bid = (int)blockIdx.x;                    // 0..1023
    const int swz = (bid & 7) * 128 + (bid >> 3);       // XCD n -> rows [n*128, n*128+128)
    const int b = swz >> 8;
    const int h = swz & (NH - 1);
    const int w0 = t << 2;
    const int pix = h * NW + w0;

    // ---- Phase 1: spatial conv per channel, park cs/pd in LDS columns ----
    #pragma unroll 1
    for (int c = 0; c < NC; ++c) {
        const float* pdd = g_d  + (size_t)(b * NC + c) * HW + pix;
        const float* pcc = g_cd + (size_t)(b * NC + c) * HW + pix;
        const float* pss = g_sp + ((size_t)(b * NC + c) * NK) * HW + pix;

        // Stencil rows -> registers (all indices compile-time after unroll).
        float dr[3][6], cr[3][6];
        #pragma unroll
        for (int r = 0; r < 3; ++r) {
            const int hh = h + r - 1;
            const int roff = (r - 1) * NW;
            if ((unsigned)hh < (unsigned)NH) {
                const float4 md = *(const float4*)(pdd + roff);
                const float4 mc = *(const float4*)(pcc + roff);
                dr[r][1] = md.x; dr[r][2] = md.y; dr[r][3] = md.z; dr[r][4] = md.w;
                cr[r][1] = mc.x; cr[r][2] = mc.y; cr[r][3] = mc.z; cr[r][4] = mc.w;
                dr[r][0] = (w0 > 0)       ? pdd[roff - 1] : 0.f;
                cr[r][0] = (w0 > 0)       ? pcc[roff - 1] : 0.f;
                dr[r][5] = (w0 + 4 < NW)  ? pdd[roff + 4] : 0.f;
                cr[r][5] = (w0 + 4 < NW)  ? pcc[roff + 4] : 0.f;
            } else {
                #pragma unroll
                for (int j = 0; j < 6; ++j) { dr[r][j] = 0.f; cr[r][j] = 0.f; }
            }
        }

        float4 sp[NK];
        #pragma unroll
        for (int k = 0; k < NK; ++k)
            sp[k] = *(const float4*)(pss + (size_t)k * HW);

        float nom[4] = {0.f, 0.f, 0.f, 0.f};
        float den[4] = {0.f, 0.f, 0.f, 0.f};
        #pragma unroll
        for (int r = 0; r < 3; ++r) {
            #pragma unroll
            for (int dj = 0; dj < 3; ++dj) {
                const int k = r * 3 + dj;
                const float wck = lds_sw[c * NK + k];      // wave-uniform -> broadcast
                const float sv[4] = {sp[k].x, sp[k].y, sp[k].z, sp[k].w};
                #pragma unroll
                for (int p = 0; p < 4; ++p) {
                    const float cdp = cr[r][dj + p] * sv[p];
                    nom[p] = fmaf(cdp * dr[r][dj + p], wck, nom[p]);
                    den[p] = fmaf(cdp, wck, den[p]);
                }
            }
        }

        float4 csv, pdv;
        csv.x = den[0] * inv_sw_sum;  pdv.x = csv.x * (nom[0] * frcp(den[0] + kEPS));
        csv.y = den[1] * inv_sw_sum;  pdv.y = csv.y * (nom[1] * frcp(den[1] + kEPS));
        csv.z = den[2] * inv_sw_sum;  pdv.z = csv.z * (nom[2] * frcp(den[2] + kEPS));
        csv.w = den[3] * inv_sw_sum;  pdv.w = csv.w * (nom[3] * frcp(den[3] + kEPS));
        *(float4*)&lds_cs[c][w0] = csv;
        *(float4*)&lds_pd[c][w0] = pdv;
    }
    // Thread-private LDS columns; single-wave block -> no barrier.

    // ---- Phase 2: 16x16 channel mix in 4 chunks of 4 out-channels ----
    const size_t outb = (size_t)b * NC * HW + pix;
    #pragma unroll 1
    for (int oc = 0; oc < 4; ++oc) {
        float4 an[4], ad[4];
        #pragma unroll
        for (int o4 = 0; o4 < 4; ++o4) {
            an[o4] = make_float4(0.f, 0.f, 0.f, 0.f);
            ad[o4] = make_float4(0.f, 0.f, 0.f, 0.f);
        }
        #pragma unroll
        for (int c = 0; c < NC; ++c) {
            const float4 pdv = *(const float4*)&lds_pd[c][w0];
            const float4 csv = *(const float4*)&lds_cs[c][w0];
            #pragma unroll
            for (int o4 = 0; o4 < 4; ++o4) {
                const float wv = lds_cw[(oc * 4 + o4) * NC + c];  // uniform -> broadcast
                an[o4].x = fmaf(pdv.x, wv, an[o4].x);
                an[o4].y = fmaf(pdv.y, wv, an[o4].y);
                an[o4].z = fmaf(pdv.z, wv, an[o4].z);
                an[o4].w = fmaf(pdv.w, wv, an[o4].w);
                ad[o4].x = fmaf(csv.x, wv, ad[o4].x);
                ad[o4].y = fmaf(csv.y, wv, ad[o4].y);
                ad[o4].z = fmaf(csv.z, wv, ad[o4].z);
                ad[o4].w = fmaf(csv.w, wv, ad[o4].w);
            }
        }
        #pragma unroll
        for (int o4 = 0; o4 < 4; ++o4) {
            const int o = oc * 4 + o4;
            float4 dv, cv;
            dv.x = an[o4].x * frcp(ad[o4].x + kEPS);
            dv.y = an[o4].y * frcp(ad[o4].y + kEPS);
            dv.z = an[o4].z * frcp(ad[o4].z + kEPS);
            dv.w = an[o4].w * frcp(ad[o4].w + kEPS);
            cv.x = ad[o4].x * inv_cw_sum;     // devalue_conf == 1
            cv.y = ad[o4].y * inv_cw_sum;
            cv.z = ad[o4].z * inv_cw_sum;
            cv.w = ad[o4].w * inv_cw_sum;
            *(float4*)(g_dout  + outb + (size_t)o * HW) = dv;
            *(float4*)(g_cdout + outb + (size_t)o * HW) = cv;
        }
    }
}

extern "C" void kernel_launch(void* const* d_in, const int* in_sizes, int n_in,
                              void* d_out, int out_size, void* d_ws, size_t ws_size,
                              hipStream_t stream) {
    const float* g_d  = (const float*)d_in[0];
    const float* g_cd = (const float*)d_in[1];
    // d_in[2] = s, d_in[3] = cs : unused by the reference computation.
    const float* g_sp = (const float*)d_in[4];
    const float* g_sw = (const float*)d_in[5];
    const float* g_cw = (const float*)d_in[6];

    float* g_dout  = (float*)d_out;
    float* g_cdout = g_dout + (size_t)NB * NC * HW;

    const int blocks = NB * NH;   // 1024 one-row blocks (64 thr, 4 px/thr)
    structnconv_fused<<<blocks, TPB, 0, stream>>>(g_d, g_cd, g_sp, g_sw, g_cw,
                                                  g_dout, g_cdout);
}

// Round 6
// 38.011 us; speedup vs baseline: 4.5257x; 1.0838x over previous
//
#include <hip/hip_runtime.h>

// StructNConv2D_d_with_s — fused spatial (3x3) + channel (16x16) normalized conv.
// d,cd: (4,16,256,256) f32; s_prod_roll: (4,16,9,256,256) f32;
// spatial_weight: (16,1,9,1,1); channel_weight: (16,16,1,1).
// Outputs concatenated: d_out then cd_out, each (4,16,256,256) f32.
//
// R6: channel-split waves for occupancy. R5 was 4 waves/CU = 1 wave/SIMD
// (grid-limited: 1024 waves at 4px/thread) -> no TLP to cover latency; 76%
// of BW floor. Now TPB=128: wave0 computes c=0..7, wave1 c=8..15 over the
// SAME 256-px row (per-iter instr cost unchanged, wave count 2x -> 2/SIMD).
// Partial channel-mix accumulators exchanged via 32KB LDS (f32, 1 barrier);
// wave w finalizes/stores output channels [8w, 8w+8). Register accumulator
// indices kept compile-time static via uniform-branch macros (R4 lesson).

#define NB 4
#define NC 16
#define NH 256
#define NW 256
#define NK 9
#define HW (NH * NW)
#define TPB 128

static constexpr float kEPS = 1e-20f;

__device__ __forceinline__ float frcp(float x) { return __builtin_amdgcn_rcpf(x); }

__global__ __launch_bounds__(TPB) void structnconv_fused(
    const float* __restrict__ g_d,
    const float* __restrict__ g_cd,
    const float* __restrict__ g_sp,   // s_prod_roll
    const float* __restrict__ g_sw,   // spatial_weight (16*9)
    const float* __restrict__ g_cw,   // channel_weight (16*16)
    float* __restrict__ g_dout,
    float* __restrict__ g_cdout)
{
    __shared__ float lds_sw[NC * NK];        // 576 B
    __shared__ float lds_cw[NC * NC];        // 1 KB
    __shared__ float lds_part[4];
    __shared__ float lds_x[2][8][2][NW];     // [writer][o_loc][an/ad][px] 32 KB

    const int t  = threadIdx.x;
    const int wv = t >> 6;        // wave id: 0 -> c 0..7, 1 -> c 8..15
    const int ln = t & 63;

    // ---- Stage weights + global sums (128 threads, 1 barrier) ----
    float s1 = g_sw[t];                       // t < 128 < 144
    float s2 = g_cw[t] + g_cw[TPB + t];
    lds_sw[t] = s1;
    lds_cw[t] = g_cw[t];
    lds_cw[TPB + t] = g_cw[TPB + t];
    if (t < NC * NK - TPB) {                  // 16 tail elements of sw
        const float v = g_sw[TPB + t];
        lds_sw[TPB + t] = v;
        s1 += v;
    }
    #pragma unroll
    for (int off = 32; off > 0; off >>= 1) {
        s1 += __shfl_down(s1, off);
        s2 += __shfl_down(s2, off);
    }
    if (ln == 0) {
        lds_part[wv]     = s1;
        lds_part[2 + wv] = s2;
    }
    __syncthreads();
    const float inv_sw_sum = frcp(lds_part[0] + lds_part[1] + kEPS);
    const float inv_cw_sum = frcp(lds_part[2] + lds_part[3] + kEPS);

    // ---- Block -> one (b,h) row (bijective XCD swizzle); thread -> 4 px ----
    const int bid = (int)blockIdx.x;                 // 0..1023
    const int swz = (bid & 7) * 128 + (bid >> 3);    // XCD n -> contiguous band
    const int b = swz >> 8;
    const int h = swz & (NH - 1);
    const int w0 = ln << 2;
    const int pix = h * NW + w0;

    // ---- Phase 1: spatial conv for this wave's 8 channels; accumulate
    //      channel-mix partials for ALL 16 output channels in registers ----
    float4 an[NC], ad[NC];
    #pragma unroll
    for (int o = 0; o < NC; ++o) {
        an[o] = make_float4(0.f, 0.f, 0.f, 0.f);
        ad[o] = make_float4(0.f, 0.f, 0.f, 0.f);
    }

    #pragma unroll 1
    for (int ci = 0; ci < 8; ++ci) {
        const int c = (wv << 3) + ci;     // wave-uniform
        const float* pdd = g_d  + (size_t)(b * NC + c) * HW + pix;
        const float* pcc = g_cd + (size_t)(b * NC + c) * HW + pix;
        const float* pss = g_sp + ((size_t)(b * NC + c) * NK) * HW + pix;

        // Stencil rows -> registers (static indices after unroll).
        float dr[3][6], cr[3][6];
        #pragma unroll
        for (int r = 0; r < 3; ++r) {
            const int hh = h + r - 1;
            const int roff = (r - 1) * NW;
            if ((unsigned)hh < (unsigned)NH) {
                const float4 md = *(const float4*)(pdd + roff);
                const float4 mc = *(const float4*)(pcc + roff);
                dr[r][1] = md.x; dr[r][2] = md.y; dr[r][3] = md.z; dr[r][4] = md.w;
                cr[r][1] = mc.x; cr[r][2] = mc.y; cr[r][3] = mc.z; cr[r][4] = mc.w;
                dr[r][0] = (w0 > 0)      ? pdd[roff - 1] : 0.f;
                cr[r][0] = (w0 > 0)      ? pcc[roff - 1] : 0.f;
                dr[r][5] = (w0 + 4 < NW) ? pdd[roff + 4] : 0.f;
                cr[r][5] = (w0 + 4 < NW) ? pcc[roff + 4] : 0.f;
            } else {
                #pragma unroll
                for (int j = 0; j < 6; ++j) { dr[r][j] = 0.f; cr[r][j] = 0.f; }
            }
        }

        float4 sp[NK];
        #pragma unroll
        for (int k = 0; k < NK; ++k)
            sp[k] = *(const float4*)(pss + (size_t)k * HW);

        float nom[4] = {0.f, 0.f, 0.f, 0.f};
        float den[4] = {0.f, 0.f, 0.f, 0.f};
        #pragma unroll
        for (int r = 0; r < 3; ++r) {
            #pragma unroll
            for (int dj = 0; dj < 3; ++dj) {
                const int k = r * 3 + dj;
                const float wck = lds_sw[c * NK + k];   // uniform -> broadcast
                const float sv[4] = {sp[k].x, sp[k].y, sp[k].z, sp[k].w};
                #pragma unroll
                for (int p = 0; p < 4; ++p) {
                    const float cdp = cr[r][dj + p] * sv[p];
                    nom[p] = fmaf(cdp * dr[r][dj + p], wck, nom[p]);
                    den[p] = fmaf(cdp, wck, den[p]);
                }
            }
        }

        float4 csv, pdv;
        csv.x = den[0] * inv_sw_sum;  pdv.x = csv.x * (nom[0] * frcp(den[0] + kEPS));
        csv.y = den[1] * inv_sw_sum;  pdv.y = csv.y * (nom[1] * frcp(den[1] + kEPS));
        csv.z = den[2] * inv_sw_sum;  pdv.z = csv.z * (nom[2] * frcp(den[2] + kEPS));
        csv.w = den[3] * inv_sw_sum;  pdv.w = csv.w * (nom[3] * frcp(den[3] + kEPS));

        // Channel-mix partial accumulation (o statically unrolled).
        #pragma unroll
        for (int o = 0; o < NC; ++o) {
            const float wcv = lds_cw[o * NC + c];       // uniform -> broadcast
            an[o].x = fmaf(pdv.x, wcv, an[o].x);
            an[o].y = fmaf(pdv.y, wcv, an[o].y);
            an[o].z = fmaf(pdv.z, wcv, an[o].z);
            an[o].w = fmaf(pdv.w, wcv, an[o].w);
            ad[o].x = fmaf(csv.x, wcv, ad[o].x);
            ad[o].y = fmaf(csv.y, wcv, ad[o].y);
            ad[o].z = fmaf(csv.z, wcv, ad[o].z);
            ad[o].w = fmaf(csv.w, wcv, ad[o].w);
        }
    }

    // ---- Exchange: write partner's o-range partials to LDS (static idx) ----
    #define XWRITE(BASE)                                                   \
        _Pragma("unroll")                                                  \
        for (int ol = 0; ol < 8; ++ol) {                                   \
            *(float4*)&lds_x[wv][ol][0][w0] = an[(BASE) + ol];             \
            *(float4*)&lds_x[wv][ol][1][w0] = ad[(BASE) + ol];             \
        }
    if (wv == 0) { XWRITE(8) } else { XWRITE(0) }
    #undef XWRITE

    __syncthreads();

    // ---- Finalize own o-range: own partial + partner partial, epilogue ----
    const size_t outb = (size_t)b * NC * HW + pix;
    #define FINISH(BASE)                                                   \
        _Pragma("unroll")                                                  \
        for (int ol = 0; ol < 8; ++ol) {                                   \
            const int o = (BASE) + ol;                                     \
            const float4 xn = *(const float4*)&lds_x[wv ^ 1][ol][0][w0];   \
            const float4 xd = *(const float4*)&lds_x[wv ^ 1][ol][1][w0];   \
            const float nx = an[o].x + xn.x, dx = ad[o].x + xd.x;          \
            const float ny = an[o].y + xn.y, dy = ad[o].y + xd.y;          \
            const float nz = an[o].z + xn.z, dz = ad[o].z + xd.z;          \
            const float nw_ = an[o].w + xn.w, dw = ad[o].w + xd.w;         \
            float4 dv, cv;                                                 \
            dv.x = nx * frcp(dx + kEPS);  cv.x = dx * inv_cw_sum;          \
            dv.y = ny * frcp(dy + kEPS);  cv.y = dy * inv_cw_sum;          \
            dv.z = nz * frcp(dz + kEPS);  cv.z = dz * inv_cw_sum;          \
            dv.w = nw_ * frcp(dw + kEPS); cv.w = dw * inv_cw_sum;          \
            *(float4*)(g_dout  + outb + (size_t)o * HW) = dv;              \
            *(float4*)(g_cdout + outb + (size_t)o * HW) = cv;              \
        }
    if (wv == 0) { FINISH(0) } else { FINISH(8) }
    #undef FINISH
}

extern "C" void kernel_launch(void* const* d_in, const int* in_sizes, int n_in,
                              void* d_out, int out_size, void* d_ws, size_t ws_size,
                              hipStream_t stream) {
    const float* g_d  = (const float*)d_in[0];
    const float* g_cd = (const float*)d_in[1];
    // d_in[2] = s, d_in[3] = cs : unused by the reference computation.
    const float* g_sp = (const float*)d_in[4];
    const float* g_sw = (const float*)d_in[5];
    const float* g_cw = (const float*)d_in[6];

    float* g_dout  = (float*)d_out;
    float* g_cdout = g_dout + (size_t)NB * NC * HW;

    const int blocks = NB * NH;   // 1024 one-row blocks, 2 c-split waves each
    structnconv_fused<<<blocks, TPB, 0, stream>>>(g_d, g_cd, g_sp, g_sw, g_cw,
                                                  g_dout, g_cdout);
}